// Round 4
// baseline (399.992 us; speedup 1.0000x reference)
//
#include <hip/hip_runtime.h>

// channel_attention: einsum('bocs,bocm->bocs', x, softmax(score)) contracts m which
// only appears in score => multiplies x by softmax row-sum == 1 (within fp32 eps).
// So q/k/atten are dead code and the problem is exactly:
//   out[g,c,s] = LN_c( sum_m Wp[c][m] * x[g][m][s] + bp[c] ) * gp[c] + betap[c]
// g = b*o in [0,128). Per group: GEMM M=C=128, N=3000, K=128, + per-column LN.
//
// V5. V4 (124us/dispatch) had exact traffic (FETCH 115 + WRITE 194 MB, floor 49us)
// but 2.58 TB/s: serial per-block phases {load, vmcnt(0), __syncthreads (drains
// vmem!), mfma, store} expose full HBM latency per tile and never overlap the
// read and write streams. V5: persistent blocks (512 = 2/CU exactly), 6 s-tiles
// each, software-pipelined: while computing/storing tile t, tile t+1's 8 f4
// loads are in flight ACROSS raw s_barriers (lgkmcnt-only drain; vmcnt never
// forced to 0 in the loop). W staged once per block. Hazards: Xl RAW = lgkm
// drain + barrier A; Xl WAR = barrier B + in-order LDS; tail tile = clamped
// load addrs (garbage col s only pollutes unstored col s).

#define C    128
#define SEQ  3000
#define NG   128
#define NT   128                       // columns per tile
#define NTILES 6
#define NBX  4                         // 24 s-tiles / 6

typedef float f4 __attribute__((ext_vector_type(4)));
typedef short short8 __attribute__((ext_vector_type(8)));

__device__ __forceinline__ unsigned short f2bf(float f) {
    union { float f; unsigned u; } v; v.f = f;
    unsigned r = v.u + 0x7fffu + ((v.u >> 16) & 1u);   // RNE
    return (unsigned short)(r >> 16);
}

// packed f32x2 -> bf16x2, RNE; dst.lo = bf16(lo), dst.hi = bf16(hi)
__device__ __forceinline__ unsigned cvt2(float lo, float hi) {
    unsigned r;
    asm("v_cvt_pk_bf16_f32 %0, %1, %2" : "=v"(r) : "v"(lo), "v"(hi));
    return r;
}

// 16B-chunk XOR swizzle: injective over 16 consecutive rows (frag reads) and over
// the transpose-write lane pattern, both verified <=2-way (V1-proven).
__device__ __forceinline__ int swz(int row, int chunk) {
    return chunk ^ ((row ^ (row >> 2)) & 15);
}

// barrier A: make ds_writes visible, sync. Does NOT drain vmcnt -> prefetch
// loads and prior stores stay in flight.
__device__ __forceinline__ void bar_lgkm() {
    asm volatile("s_waitcnt lgkmcnt(0)\n\ts_barrier" ::: "memory");
}
// barrier B: execution sync only (readers' ds_reads are drained by their own
// MFMA data deps before arriving).
__device__ __forceinline__ void bar_raw() {
    asm volatile("s_barrier" ::: "memory");
}

// Writes W in bf16 with the LDS swizzle pre-applied, so the GEMM kernel's
// W-staging is a pure linear copy.
__global__ void cvt_wp(const float* __restrict__ Wp, unsigned short* __restrict__ out) {
    int i = blockIdx.x * 256 + threadIdx.x;
    if (i >= C * C) return;
    int c = i >> 7, r = i & 127, ch = r >> 3, j = r & 7;
    out[c * C + swz(c, ch) * 8 + j] = f2bf(Wp[i]);
}

__global__ __launch_bounds__(512, 4) void gemm_ln_mfma(
    const float* __restrict__ x,             // [NG][C][SEQ] fp32
    const unsigned short* __restrict__ wbf,  // [C][C] bf16, swizzled chunk layout
    const float* __restrict__ bp,
    const float* __restrict__ gp,
    const float* __restrict__ bep,
    float* __restrict__ out)                 // [NG][C][SEQ] fp32
{
    __shared__ __align__(16) unsigned short Wl[C * C];   // 32 KB, [c][m] swizzled
    __shared__ __align__(16) unsigned short Xl[NT * C];  // 32 KB, [s][m] swizzled

    const int g  = blockIdx.y;
    const int bx = blockIdx.x;
    const float* xg = x + (size_t)g * (C * SEQ);
    float* og = out + (size_t)g * (C * SEQ);
    const int t = threadIdx.x;

    // ---- stage W once per block: linear uint4 copy (swizzle pre-applied)
    {
        const uint4* wsrc = (const uint4*)wbf;
        uint4* wdst = (uint4*)Wl;
        #pragma unroll
        for (int i = 0; i < 4; ++i) wdst[t + 512 * i] = wsrc[t + 512 * i];
    }

    // staging geometry: thread owns (m-chunk, s-quad)
    const int sq  = t & 31;              // s-quad 0..31 (consecutive lanes -> coalesced)
    const int mc  = t >> 5;              // m-chunk 0..15
    const int s_loc = 4 * sq;

    // compute geometry: wave owns 16-s strip x all 128 channels
    const int w    = t >> 6;
    const int lane = t & 63;
    const int col  = lane & 15;
    const int quad = lane >> 4;
    const int srow = 16 * w + col;

    const int s_base = bx * (NTILES * NT);

    // ---- prefetch tile 0 (clamped: tail-tile garbage cols are never stored)
    f4 r[8];
    {
        int sgl = s_base + s_loc;
        int sc  = sgl > (SEQ - 4) ? (SEQ - 4) : sgl;
        const float* xp = xg + (size_t)(mc * 8) * SEQ + sc;
        #pragma unroll
        for (int rr = 0; rr < 8; ++rr) r[rr] = *(const f4*)(xp + (size_t)rr * SEQ);
    }

    #pragma unroll 1
    for (int tt = 0; tt < NTILES; ++tt) {
        const int s0 = s_base + tt * NT;

        // ---- consume prefetch: 8x4 in-register transpose -> bf16 pairs
        uint4 pk[4];
        #pragma unroll
        for (int j = 0; j < 4; ++j) {
            pk[j].x = cvt2(r[0][j], r[1][j]);
            pk[j].y = cvt2(r[2][j], r[3][j]);
            pk[j].z = cvt2(r[4][j], r[5][j]);
            pk[j].w = cvt2(r[6][j], r[7][j]);
        }

        // ---- issue next tile's loads NOW; they fly across both barriers and
        // land under tile tt's compute/store phase.
        if (tt + 1 < NTILES) {
            int sgl = s0 + NT + s_loc;
            int sc  = sgl > (SEQ - 4) ? (SEQ - 4) : sgl;
            const float* xp = xg + (size_t)(mc * 8) * SEQ + sc;
            #pragma unroll
            for (int rr = 0; rr < 8; ++rr) r[rr] = *(const f4*)(xp + (size_t)rr * SEQ);
        }

        // ---- LDS transpose-write
        #pragma unroll
        for (int j = 0; j < 4; ++j) {
            const int sl = s_loc + j;
            *(uint4*)&Xl[sl * C + swz(sl, mc) * 8] = pk[j];
        }

        bar_lgkm();   // Xl (and W on first iter) visible; vmem stays in flight

        // ---- MFMA: D = W x X^T, col(lane&15)=s, row(4*quad+r)=c
        f4 acc[8];
        #pragma unroll
        for (int mt = 0; mt < 8; ++mt) acc[mt] = (f4){0.f, 0.f, 0.f, 0.f};

        #pragma unroll 1
        for (int kc = 0; kc < 4; ++kc) {
            short8 xb = *(const short8*)&Xl[srow * C + swz(srow, 4 * kc + quad) * 8];
            short8 a[8];
            #pragma unroll
            for (int mt = 0; mt < 8; ++mt) {
                const int row = 16 * mt + col;
                a[mt] = *(const short8*)&Wl[row * C + swz(row, 4 * kc + quad) * 8];
            }
            #pragma unroll
            for (int mt = 0; mt < 8; ++mt)
                acc[mt] = __builtin_amdgcn_mfma_f32_16x16x32_bf16(a[mt], xb, acc[mt], 0, 0, 0);
        }

        // ---- bias + in-wave per-s LayerNorm (c spans quads + regs)
        #pragma unroll
        for (int mt = 0; mt < 8; ++mt) {
            const f4 b4 = *(const f4*)(bp + 16 * mt + 4 * quad);
            #pragma unroll
            for (int rr = 0; rr < 4; ++rr) acc[mt][rr] += b4[rr];
        }

        float s = 0.f, q = 0.f;
        #pragma unroll
        for (int mt = 0; mt < 8; ++mt)
            #pragma unroll
            for (int rr = 0; rr < 4; ++rr) {
                float y = acc[mt][rr];
                s += y; q += y * y;
            }
        s += __shfl_xor(s, 16); q += __shfl_xor(q, 16);
        s += __shfl_xor(s, 32); q += __shfl_xor(q, 32);
        const float mean = s * (1.0f / C);
        const float var  = q * (1.0f / C) - mean * mean;
        const float rstd = rsqrtf(var + 1e-5f);

        // ---- scale/shift + store: 16 lanes x 4B contiguous = full 64B sector
        const int sg = s0 + srow;
        if (sg < SEQ) {
            #pragma unroll
            for (int mt = 0; mt < 8; ++mt) {
                const f4 g4 = *(const f4*)(gp  + 16 * mt + 4 * quad);
                const f4 e4 = *(const f4*)(bep + 16 * mt + 4 * quad);
                #pragma unroll
                for (int rr = 0; rr < 4; ++rr) {
                    const int c = 16 * mt + 4 * quad + rr;
                    og[(size_t)c * SEQ + sg] =
                        (acc[mt][rr] - mean) * rstd * g4[rr] + e4[rr];
                }
            }
        }

        bar_raw();    // Xl safe to overwrite; stores/loads remain in flight
    }
}

extern "C" void kernel_launch(void* const* d_in, const int* in_sizes, int n_in,
                              void* d_out, int out_size, void* d_ws, size_t ws_size,
                              hipStream_t stream) {
    // inputs: x, Wq, bq, gq, betaq, Wk, bk, gk, betak, Wp, bp, gp, betap
    const float* x   = (const float*)d_in[0];
    const float* Wp  = (const float*)d_in[9];
    const float* bp  = (const float*)d_in[10];
    const float* gp  = (const float*)d_in[11];
    const float* bep = (const float*)d_in[12];
    float* out = (float*)d_out;
    unsigned short* wbf = (unsigned short*)d_ws;   // 32 KB bf16 weights (swizzled)

    hipLaunchKernelGGL(cvt_wp, dim3(64), dim3(256), 0, stream, Wp, wbf);

    dim3 grid(NBX, NG);
    hipLaunchKernelGGL(gemm_ln_mfma, grid, dim3(512), 0, stream,
                       x, wbf, bp, gp, bep, out);
}